// Round 8
// baseline (249.504 us; speedup 1.0000x reference)
//
#include <hip/hip_runtime.h>
#include <math.h>

// Problem constants
#define K_    1024
#define N_    32768
#define NELEM 8388608

// d_out layout (floats, reference return order)
#define Q_OFF    1
#define PERP_OFF 8388609
#define IDX_OFF  8388610

// d_out Q-region scratch (overwritten by k_gather at the end)
#define XLO_F_OFF 4          // xlo frag: 32768*256 fp16

typedef unsigned long long ull;
typedef _Float16 h8  __attribute__((ext_vector_type(8)));
typedef float    f4v __attribute__((ext_vector_type(4)));

// ws layout (bytes)
#define WS_COUNTS  0        // 1024 u32
#define WS_SUMSQ   4096     // double (legacy, unused by gather now)
#define WS_RISKCNT 4104     // u32
#define WS_DONE    4108     // u32
#define WS_EN2     4160     // 1024 f32
#define WS_XN2     8256     // 32768 f32
#define WS_IDX     139328   // 32768 i32
#define WS_RLIST   270400   // 32768 i32; REUSED by k_gather as 1024 f64 partials
#define WS_RKEY    401472   // 32768 u64
#define WS_EHI     663616   // 1024*256 fp16 (fragment-major)
#define WS_XHI     1187904  // 32768*256 fp16 (fragment-major)

// es LDS leading-dim: 133 (not 132) -> stores are 2-way instead of 8-way
// bank-conflicted (528a mod 32 = {0,16}; 532a mod 32 has period 8).
#define ES_LD 133

// risky-gap threshold, quantized (1/1024-scaled-distance grid):
// W = 0.20 scaled -> 205 grid + 2 quantization slack. Covers ref f32
// rounding (0.066) + 2x sweep dot error (max ~0.027 at 6 sigma; 15 sigma
// would be needed to break 0.134) + <=0.1 grid fused-epilogue rounding
// delta (enQ pre-fusion, see k_sweep). Flagged pixels get exact f32 rescan.
#define RISKY_Q 207u

// REGISTER LAW (R4/R5/R6, three spill storms): __launch_bounds__ min-waves
// is a register-allocator COMMAND, and on gfx950's unified file the arch
// partition lands on coarse boundaries (observed 84/128, never ~160). Any
// k_sweep variant whose arch demand exceeds the boundary below (cap - acc)
// spills catastrophically (WRITE_SIZE 95-340 MB tripwire). The ONLY verified
// no-spill sweep shape is: 64-px tile, 4 waves, acc=128 AGPR, (256,2).
// Arch budget check BEFORE any change: arch + 128 acc must stay <= 256.
// R8 ping-pong prefetch: ~100 + 16 + 128 = 244 <= 256 -> predicted clean.

__device__ __forceinline__ unsigned u32min(unsigned a, unsigned b) { return a < b ? a : b; }
__device__ __forceinline__ unsigned u32max(unsigned a, unsigned b) { return a > b ? a : b; }

// Release ordering for a preceding device-scope atomic WITHOUT the
// agent-scope fence's buffer_wbl2/buffer_inv (XCD-L2 writeback+invalidate
// storm). The atomic already executed at the coherent point; we only need
// its completion before the next atomic issues.
__device__ __forceinline__ void vmem_drain() {
    asm volatile("s_waitcnt vmcnt(0)" ::: "memory");
}

// ---------------------------------------------------------------------------
// k_pre: blocks 0..511: x -> fragment-major fp16 hi/lo + xn2.
//        blocks 512..527: codebook -> fragment-major fp16 hi + en2.
//        blocks 528..591: rkey init (+ block 528: counts/rcnt/done/sumsq).
// Fragment layout (halfwords):
//   xf: [pixblock 512][dc 8][pi 4][lane 64][j 8]; pixel=pi*16+(lane&15),
//       d = dc*32 + (lane>>4)*8 + j
//   ef: [kt 4][w 4][dc 8][ci 4][lane 64][j 8]; code=kt*256+w*64+ci*16+(lane&15)
__global__ __launch_bounds__(256) void k_pre(const float* __restrict__ x,
                                             const float* __restrict__ cb,
                                             ushort* __restrict__ xfh,
                                             ushort* __restrict__ xfl,
                                             float* __restrict__ xn2,
                                             ushort* __restrict__ efh,
                                             float* __restrict__ en2,
                                             ull* __restrict__ rkey,
                                             unsigned* __restrict__ counts,
                                             unsigned* __restrict__ rcnt,
                                             unsigned* __restrict__ done,
                                             double* __restrict__ sumsq) {
    __shared__ float T[256 * 68];
    __shared__ double red[256];
    const int t = threadIdx.x, bid = blockIdx.x;

    if (bid < 512) {
        const int b = bid >> 4, hw0 = (bid & 15) << 6;
        const float* xb = x + b * 262144 + hw0;
        // stage [c][p], quad-swizzled so frag reads are <=2-way bank aliased
#pragma unroll
        for (int i = 0; i < 16; ++i) {
            const int jv = i * 256 + t, c = jv >> 4, p4 = (jv & 15) << 2;
            const int sw = ((c >> 3) & 3) << 3;
            *(float4*)(&T[c * 68 + (p4 ^ sw)]) = *(const float4*)(xb + c * 1024 + p4);
        }
        __syncthreads();
        const int mi = t >> 6, lane = t & 63;
        const int quad = (t >> 4) & 3, l15 = t & 15;
        const int pxs = (mi * 16 + l15) ^ (quad << 3);
        double sn = 0.0;
        const size_t obase = (size_t)bid * 16384 + lane * 8;
#pragma unroll
        for (int dc = 0; dc < 8; ++dc) {
            union { _Float16 h[8]; int4 v; } ph, pl;
#pragma unroll
            for (int j = 0; j < 8; ++j) {
                const float v = T[(dc * 32 + quad * 8 + j) * 68 + pxs];
                sn += (double)v * v;
                const _Float16 hi = (_Float16)v;
                ph.h[j] = hi;
                pl.h[j] = (_Float16)((v - (float)hi) * 2048.0f);
            }
            *(int4*)(xfh + obase + (dc * 4 + mi) * 512) = ph.v;
            *(int4*)(xfl + obase + (dc * 4 + mi) * 512) = pl.v;
        }
        red[t] = sn;
        __syncthreads();
        if (t < 64) {
            const int base = (t >> 4) * 64 + (t & 15);
            xn2[bid * 64 + t] = (float)(red[base] + red[base + 16] +
                                        red[base + 32] + red[base + 48]);
        }
    } else if (bid < 528) {
        const int n = (bid - 512) * 64 + (t >> 2);
        const int seg = t & 3;
        const float* src = cb + (size_t)n * 256 + seg * 64;
        const int kt = n >> 8, wch = (n >> 6) & 3, ci = (n >> 4) & 3, l15 = n & 15;
        double s = 0.0;
#pragma unroll
        for (int g = 0; g < 8; ++g) {
            const float4 a = *(const float4*)(src + g * 8);
            const float4 b = *(const float4*)(src + g * 8 + 4);
            s += (double)a.x * a.x + (double)a.y * a.y + (double)a.z * a.z + (double)a.w * a.w;
            s += (double)b.x * b.x + (double)b.y * b.y + (double)b.z * b.z + (double)b.w * b.w;
            const float v[8] = {a.x, a.y, a.z, a.w, b.x, b.y, b.z, b.w};
            union { _Float16 h[8]; int4 q; } ph;
#pragma unroll
            for (int j = 0; j < 8; ++j)
                ph.h[j] = (_Float16)(v[j] * 1024.0f);          // exact pow2 scale
            const int dc = seg * 2 + (g >> 2);
            const int quad = g & 3;
            const size_t addr = ((size_t)(((kt * 4 + wch) * 8 + dc) * 4 + ci) * 64 +
                                 (quad * 16 + l15)) * 8;
            *(int4*)(efh + addr) = ph.q;
        }
        red[t] = s;
        __syncthreads();
        if (t < 64) {
            const int r2 = (bid - 512) * 64 + t;
            en2[r2] = (float)(red[t * 4] + red[t * 4 + 1] + red[t * 4 + 2] + red[t * 4 + 3]);
        }
    } else {
        const int ib = bid - 528;
        const int i0 = ib * 512 + t * 2;
        rkey[i0] = ~0ull; rkey[i0 + 1] = ~0ull;
        if (ib == 0) {
            ((uint4*)counts)[t] = make_uint4(0u, 0u, 0u, 0u);
            if (t == 0) { *rcnt = 0u; *done = 0u; *sumsq = 0.0; }
        }
    }
}

// ---------------------------------------------------------------------------
// 2-chain fp16 MFMA sweep, register epilogue — verified R3 shape (4 waves,
// 64 px x 1024 codes, acc=128 AGPR) + fused enQ epilogue (validated R4-R7)
// + R8: software-pipelined A-operand prefetch. Ping-pong pair ahA/ahB
// (+16 VGPR, no reg-reg copies): while the MFMA block for dc runs, the 4
// L2 loads for dc+1 are in flight; the prefetch of (kt+1, dc=0) issues
// BEFORE kt's epilogue, so ~400cy of epilogue VALU hides the cold-start
// load latency at each kt boundary. Arch ~116 + acc 128 = 244 <= 256.
// D layout: col(lane&15)=pixel, row(quad*4+reg)=code -> each lane owns 4
// pixels x 16 codes: per-pixel top-2 in registers as quantized u32 keys.
// enQ = en2*2^20 + 131072; qf = fmaf(-2048, acc_hi, enQ) - acc_lo.
__global__ __launch_bounds__(256, 2) void k_sweep(const float* __restrict__ x,
                                                  ushort* __restrict__ xfh,
                                                  ushort* __restrict__ xfl,
                                                  const ushort* __restrict__ efh,
                                                  const float* __restrict__ en2,
                                                  int* __restrict__ idxv,
                                                  int* __restrict__ rlist,
                                                  unsigned* __restrict__ rcnt) {
    __shared__ __align__(16) ushort Bsh[16384];   // 32 KB: pixel-hi frags
    __shared__ __align__(16) ushort Bsl[16384];   // 32 KB: pixel-lo frags
    __shared__ __align__(16) float  enS[1024];    // 4 KB: fused norm keys
    __shared__ unsigned Mg[4][64][2];             // 2 KB: per-wave top-2
    __shared__ int rpixS[64];                     // local risky pixel list
    __shared__ int rnS;

    const int t = threadIdx.x, bid = blockIdx.x;
    const int p0 = bid << 6;
    const int w = t >> 6, lane = t & 63;
    const int quad = lane >> 4, l15 = lane & 15;

    {   // stage this block's 64 pixels (hi+lo) + fused norm keys
        const size_t base = (size_t)bid * 16384;
#pragma unroll
        for (int i = 0; i < 8; ++i) {
            const int off = (i * 256 + t) * 8;
            *(int4*)(&Bsh[off]) = *(const int4*)(xfh + base + off);
            *(int4*)(&Bsl[off]) = *(const int4*)(xfl + base + off);
        }
#pragma unroll
        for (int i = 0; i < 4; ++i)
            enS[i * 256 + t] = fmaf(en2[i * 256 + t], 1048576.0f, 131072.0f);
    }
    __syncthreads();
    // From here on the global xfh/xfl segments of THIS block are dead
    // (only block bid ever reads segment bid) -> reusable as x_t scratch.

    unsigned K1[4], K2[4];   // running top-2 per pixel (ni*16+l15)
#pragma unroll
    for (int ni = 0; ni < 4; ++ni) { K1[ni] = 0xFFFFFFFFu; K2[ni] = 0xFFFFFFFFu; }

    // A-frag address for linear tile u = kt*8+dc (this wave's 64 codes):
    // abase(u) = ((((u>>3)*4 + w)*8 + (u&7))*4)*512 + lane*8
    const int lane8 = lane * 8;
    h8 ahA[4], ahB[4];
    {   // preload u = 0 (kt=0, dc=0)
        const size_t a0 = ((size_t)(w * 8) * 4) * 512 + lane8;
#pragma unroll
        for (int mi = 0; mi < 4; ++mi)
            ahA[mi] = *(const h8*)(efh + a0 + mi * 512);
    }

    for (int kt = 0; kt < 4; ++kt) {
        const f4v z = {0.f, 0.f, 0.f, 0.f};
        f4v acc1[4][4], acc2[4][4];
#pragma unroll
        for (int mi = 0; mi < 4; ++mi)
#pragma unroll
            for (int ni = 0; ni < 4; ++ni) { acc1[mi][ni] = z; acc2[mi][ni] = z; }

#pragma unroll
        for (int dch = 0; dch < 4; ++dch) {
            const int u = kt * 8 + dch * 2;
            {   // prefetch u+1 -> ahB (u+1 <= 31 always here)
                const int nu = u + 1;
                const size_t ab = ((size_t)(((nu >> 3) * 4 + w) * 8 + (nu & 7)) * 4) * 512 + lane8;
#pragma unroll
                for (int mi = 0; mi < 4; ++mi)
                    ahB[mi] = *(const h8*)(efh + ab + mi * 512);
            }
            {   // MFMA block for dc = u&7 using ahA (resident)
                const int bbase = (u & 7) * 2048 + lane8;
#pragma unroll
                for (int ni = 0; ni < 4; ++ni) {
                    const h8 bh = *(const h8*)(&Bsh[bbase + ni * 512]);
                    const h8 bl = *(const h8*)(&Bsl[bbase + ni * 512]);
#pragma unroll
                    for (int mi = 0; mi < 4; ++mi) {
                        acc1[mi][ni] = __builtin_amdgcn_mfma_f32_16x16x32_f16(
                            ahA[mi], bh, acc1[mi][ni], 0, 0, 0);
                        acc2[mi][ni] = __builtin_amdgcn_mfma_f32_16x16x32_f16(
                            ahA[mi], bl, acc2[mi][ni], 0, 0, 0);
                    }
                }
            }
            {   // prefetch u+2 -> ahA (clamped: u=30 -> reload 31, harmless)
                const int nu = (u + 2 > 31) ? 31 : (u + 2);
                const size_t ab = ((size_t)(((nu >> 3) * 4 + w) * 8 + (nu & 7)) * 4) * 512 + lane8;
#pragma unroll
                for (int mi = 0; mi < 4; ++mi)
                    ahA[mi] = *(const h8*)(efh + ab + mi * 512);
            }
            {   // MFMA block for dc = (u+1)&7 using ahB
                const int bbase = ((u + 1) & 7) * 2048 + lane8;
#pragma unroll
                for (int ni = 0; ni < 4; ++ni) {
                    const h8 bh = *(const h8*)(&Bsh[bbase + ni * 512]);
                    const h8 bl = *(const h8*)(&Bsl[bbase + ni * 512]);
#pragma unroll
                    for (int mi = 0; mi < 4; ++mi) {
                        acc1[mi][ni] = __builtin_amdgcn_mfma_f32_16x16x32_f16(
                            ahB[mi], bh, acc1[mi][ni], 0, 0, 0);
                        acc2[mi][ni] = __builtin_amdgcn_mfma_f32_16x16x32_f16(
                            ahB[mi], bl, acc2[mi][ni], 0, 0, 0);
                    }
                }
            }
        }
        // register epilogue: 64 dists -> quantized keys -> top-2 per pixel.
        // (kt+1, dc=0) A-loads are already in flight above this point.
#pragma unroll
        for (int mi = 0; mi < 4; ++mi) {
            const int cbase = kt * 256 + w * 64 + mi * 16 + quad * 4;
            const f4v enQ = *(const f4v*)(&enS[cbase]);   // b128, broadcast/2-way
#pragma unroll
            for (int ni = 0; ni < 4; ++ni) {
#pragma unroll
                for (int r = 0; r < 4; ++r) {
                    const float t0 = fmaf(-2048.0f, acc1[mi][ni][r], enQ[r]);
                    const float qf = t0 - acc2[mi][ni][r];
                    const unsigned key = ((unsigned)(int)qf << 10) | (unsigned)(cbase + r);
                    const unsigned o1 = K1[ni];
                    K1[ni] = u32min(o1, key);
                    K2[ni] = u32min(K2[ni], u32max(o1, key));
                }
            }
        }
    }
    // cross-quad merge (disjoint code sets, same pixels): xor 16, 32
#pragma unroll
    for (int m = 16; m <= 32; m <<= 1) {
#pragma unroll
        for (int ni = 0; ni < 4; ++ni) {
            const unsigned a1 = (unsigned)__shfl_xor((int)K1[ni], m, 64);
            const unsigned a2 = (unsigned)__shfl_xor((int)K2[ni], m, 64);
            const unsigned n1 = u32min(K1[ni], a1);
            const unsigned n2 = u32min(u32max(K1[ni], a1), u32min(K2[ni], a2));
            K1[ni] = n1; K2[ni] = n2;
        }
    }
    if (quad == 0) {
#pragma unroll
        for (int ni = 0; ni < 4; ++ni) {
            Mg[w][ni * 16 + l15][0] = K1[ni];
            Mg[w][ni * 16 + l15][1] = K2[ni];
        }
    }
    __syncthreads();
    if (t < 64) {   // cross-wave merge (disjoint code sets per wave)
        unsigned b1 = Mg[0][t][0], b2 = Mg[0][t][1];
#pragma unroll
        for (int ww = 1; ww < 4; ++ww) {
            const unsigned a1 = Mg[ww][t][0], a2 = Mg[ww][t][1];
            const unsigned n1 = u32min(b1, a1);
            b2 = u32min(u32max(b1, a1), u32min(b2, a2));
            b1 = n1;
        }
        const int P = p0 + t;
        idxv[P] = (int)(b1 & 1023u);
        const bool risky = ((b2 >> 10) - (b1 >> 10)) <= RISKY_Q;
        const ull mask = __ballot(risky);
        const int pre = __popcll(mask & ((1ull << t) - 1ull));
        unsigned base = 0;
        if (t == 0) { base = atomicAdd(rcnt, (unsigned)__popcll(mask)); rnS = (int)__popcll(mask); }
        base = (unsigned)__shfl((int)base, 0, 64);
        if (risky) { rlist[base + pre] = P; rpixS[pre] = t; }
    }
    __syncthreads();
    // x_t gather: exact f32 rows for this block's risky pixels into the
    // block's own dead frag segments. Wave-parallel over risky pixels; each
    // lane fetches 4 channels (4 stride-4096B scalar loads -> 4 lines) and
    // stores one contiguous float4 to the x_t row.
    {
        const int rn = rnS;
        float* xth = (float*)(xfh + (size_t)bid * 16384);   // 64 px * 128 f32
        float* xtl = (float*)(xfl + (size_t)bid * 16384);
        for (int i = w; i < rn; i += 4) {
            const int lp = rpixS[i];
            const int P = p0 + lp;
            const float* xp = x + (size_t)(P >> 10) * 262144 + (P & 1023);
            const int c0 = lane * 4;
            float4 vv;
            vv.x = xp[(size_t)(c0 + 0) * 1024];
            vv.y = xp[(size_t)(c0 + 1) * 1024];
            vv.z = xp[(size_t)(c0 + 2) * 1024];
            vv.w = xp[(size_t)(c0 + 3) * 1024];
            float* dst = (c0 < 128) ? (xth + lp * 128 + c0)
                                    : (xtl + lp * 128 + (c0 - 128));
            *(float4*)dst = vv;
        }
    }
}

// ---------------------------------------------------------------------------
// Exact f32 rescan of risky pixels (validated: replicates np ref numerics).
// x is read from x_t (pixel-major exact f32 rows written by k_sweep into
// the dead xfh/xfl segments): per thread 4x float4 from ONE cache line,
// L2-resident, instead of 16 stride-4096 scalar gathers (16 lines) re-done
// per kt-unit. Staged values and accumulation order are bit-identical.
__global__ __launch_bounds__(256) void k_rescan(const float* __restrict__ xth,
                                                const float* __restrict__ xtl,
                                                const float* __restrict__ cb,
                                                const float* __restrict__ en2,
                                                const float* __restrict__ xn2,
                                                const int* __restrict__ rlist,
                                                const unsigned* __restrict__ rcnt,
                                                ull* __restrict__ rkey) {
    __shared__ float xs[64 * 68];
    __shared__ float es[64 * ES_LD];
    __shared__ int plist[64];
    const int t = threadIdx.x;
    const unsigned cnt = *rcnt;
    const int nunits = (int)(((cnt + 63) >> 6) << 3);
    const int ti = t >> 4, tj = t & 15;

    for (int u = blockIdx.x; u < nunits; u += gridDim.x) {
        const int tile = u >> 3, kt = u & 7;
        __syncthreads();
        if (t < 64) {
            const int li = tile * 64 + t;
            plist[t] = rlist[li < (int)cnt ? li : 0];
        }
        __syncthreads();

        float xnr[4]; int pid[4];
#pragma unroll
        for (int r = 0; r < 4; ++r) {
            pid[r] = plist[ti * 4 + r];
            xnr[r] = xn2[pid[r]];
        }
        float acc[4][8];
#pragma unroll
        for (int r = 0; r < 4; ++r)
#pragma unroll
            for (int j = 0; j < 8; ++j) acc[r][j] = 0.f;
        float best_s[4]; int best_k[4];
#pragma unroll
        for (int r = 0; r < 4; ++r) { best_s[r] = INFINITY; best_k[r] = 0; }

        for (int dc = 0; dc < 4; ++dc) {
            __syncthreads();
            {   // coalesced x_t stage: 64 B contiguous per thread
                const int p = t & 63, coff = t >> 6;
                const int P = plist[p];
                const size_t rbase = (size_t)(P >> 6) * 8192 + (size_t)(P & 63) * 128;
                const int c0 = dc * 64 + coff * 16;
                const float* src = (c0 < 128) ? (xth + rbase + c0)
                                              : (xtl + rbase + (c0 - 128));
#pragma unroll
                for (int q = 0; q < 4; ++q) {
                    const float4 v = *(const float4*)(src + q * 4);
                    const int cl = coff * 16 + q * 4;
                    xs[(cl + 0) * 68 + p] = v.x;
                    xs[(cl + 1) * 68 + p] = v.y;
                    xs[(cl + 2) * 68 + p] = v.z;
                    xs[(cl + 3) * 68 + p] = v.w;
                }
            }
#pragma unroll
            for (int i = 0; i < 8; ++i) {
                const int jv = i * 256 + t, k = jv >> 4, d4 = (jv & 15) << 2;
                const float4 v = *(const float4*)(cb + (size_t)(kt * 128 + k) * 256 + dc * 64 + d4);
                es[(d4 + 0) * ES_LD + k] = v.x; es[(d4 + 1) * ES_LD + k] = v.y;
                es[(d4 + 2) * ES_LD + k] = v.z; es[(d4 + 3) * ES_LD + k] = v.w;
            }
            __syncthreads();
#pragma unroll 4
            for (int d = 0; d < 64; ++d) {
                const float4 xv = *(const float4*)(&xs[d * 68 + ti * 4]);
                const float4 e0 = *(const float4*)(&es[d * ES_LD + tj * 8]);
                const float4 e1 = *(const float4*)(&es[d * ES_LD + tj * 8 + 4]);
                const float xr[4] = {xv.x, xv.y, xv.z, xv.w};
                const float ej[8] = {e0.x, e0.y, e0.z, e0.w, e1.x, e1.y, e1.z, e1.w};
#pragma unroll
                for (int r = 0; r < 4; ++r)
#pragma unroll
                    for (int j = 0; j < 8; ++j)
                        acc[r][j] = fmaf(xr[r], ej[j], acc[r][j]);
            }
        }
#pragma unroll
        for (int j = 0; j < 8; ++j) {
            const int k = kt * 128 + tj * 8 + j;
            const float en = en2[k];
#pragma unroll
            for (int r = 0; r < 4; ++r) {
                const float s1 = xnr[r] + en;
                const float dist = fmaf(-2.f, acc[r][j], s1);
                if (dist < best_s[r] || (dist == best_s[r] && k < best_k[r])) {
                    best_s[r] = dist; best_k[r] = k;
                }
            }
        }
#pragma unroll
        for (int r = 0; r < 4; ++r) {
            float s = best_s[r]; int k = best_k[r];
            for (int m = 1; m < 16; m <<= 1) {
                const float s2 = __shfl_xor(s, m, 64);
                const int k2 = __shfl_xor(k, m, 64);
                if (s2 < s || (s2 == s && k2 < k)) { s = s2; k = k2; }
            }
            if (tj == 0 && (tile * 64 + ti * 4 + r) < (int)cnt) {
                const ull key = ((ull)__float_as_uint(s) << 32) | (unsigned)k;  // dist>0
                atomicMin(&rkey[pid[r]], key);
            }
        }
    }
}

// ---------------------------------------------------------------------------
// Gather (+resolve fused) -> q_out, (q-x)^2 sum, histogram, idx_f; the LAST
// block (device-scope done-counter) computes loss + perplexity.
// NOTE: no __threadfence() anywhere — on gfx950 an agent-scope fence emits
// buffer_wbl2/buffer_inv (full XCD-L2 writeback+invalidate). 1024 blocks
// each flushing/invalidating the L2 mid-stream was the serializer. The only
// ordering needed (psum atomicExch completes before done increment) is a
// plain s_waitcnt vmcnt(0): both ops are device-scope atomics at the
// coherent point.
__global__ __launch_bounds__(256) void k_gather(const float* __restrict__ x,
                                                const float* __restrict__ cb,
                                                const int* __restrict__ idxv,
                                                const ull* __restrict__ rkey,
                                                float* __restrict__ out,
                                                double* __restrict__ psum,
                                                unsigned* __restrict__ counts,
                                                unsigned* __restrict__ done) {
    __shared__ __align__(16) float cs[32 * 260];
    __shared__ int   kidx[32];
    __shared__ float wpart[4];
    __shared__ int   lastf;
    __shared__ double part[256];
    __shared__ double part2[256];

    const int t = threadIdx.x, bid = blockIdx.x;
    const int n0 = bid * 32;
    if (t < 32) {
        const int n = n0 + t;
        const ull rk = rkey[n];
        const int kk = (rk != ~0ull) ? (int)(unsigned)(rk & 0xffffffffu) : idxv[n];
        kidx[t] = kk;
        atomicAdd(&counts[kk], 1u);
        out[IDX_OFF + n] = (float)kk;
    }
    if (t == 0) lastf = 0;
    __syncthreads();
#pragma unroll
    for (int i = 0; i < 8; ++i) {
        int jv = (i << 8) + t;
        int p = jv >> 6, c4 = (jv & 63) << 2;
        const float4 v = *(const float4*)(cb + (size_t)kidx[p] * 256 + c4);
        *(float4*)(&cs[p * 260 + c4]) = v;
    }
    __syncthreads();

    const int b = bid >> 5, h = bid & 31;
    const float* xb = x + b * 262144 + h * 32;
    float* qb = out + Q_OFF + b * 262144 + h * 32;

    float local = 0.f;
#pragma unroll
    for (int i = 0; i < 8; ++i) {
        int j = (i << 8) + t;
        int c = j >> 3, w4 = (j & 7) << 2;
        const float q0 = cs[(w4 + 0) * 260 + c];
        const float q1 = cs[(w4 + 1) * 260 + c];
        const float q2 = cs[(w4 + 2) * 260 + c];
        const float q3 = cs[(w4 + 3) * 260 + c];
        const float4 xv = *(const float4*)(xb + c * 1024 + w4);
        const float d0 = q0 - xv.x, d1 = q1 - xv.y;
        const float d2 = q2 - xv.z, d3 = q3 - xv.w;
        local += d0 * d0 + d1 * d1 + d2 * d2 + d3 * d3;
        qb[c * 1024 + w4 + 0] = q0;
        qb[c * 1024 + w4 + 1] = q1;
        qb[c * 1024 + w4 + 2] = q2;
        qb[c * 1024 + w4 + 3] = q3;
    }
    for (int m = 32; m > 0; m >>= 1) local += __shfl_down(local, m, 64);
    if ((t & 63) == 0) wpart[t >> 6] = local;
    __syncthreads();
    if (t == 0) {
        const double bs = (double)wpart[0] + (double)wpart[1] +
                          (double)wpart[2] + (double)wpart[3];
        // contention-free: native 64b exchange to this block's own slot
        atomicExch((ull*)&psum[bid], (ull)__double_as_longlong(bs));
        vmem_drain();   // release: swap reached coherent point; NO wbl2/inv
        if (atomicAdd(done, 1u) == 1023u) lastf = 1;
    }
    __syncthreads();
    if (lastf) {
        double s = 0.0, ss = 0.0;
        for (int k = t; k < K_; k += 256) {
            const unsigned c = atomicAdd(&counts[k], 0u);   // coherent read
            const double p = (double)c / (double)N_;
            s += p * log(p + 1e-10);
        }
#pragma unroll
        for (int i = 0; i < 4; ++i) {
            const ull pv = atomicAdd((ull*)&psum[i * 256 + t], 0ull);  // coherent read
            ss += __longlong_as_double((long long)pv);
        }
        part[t] = s; part2[t] = ss;
        __syncthreads();
        for (int off = 128; off > 0; off >>= 1) {
            if (t < off) { part[t] += part[t + off]; part2[t] += part2[t + off]; }
            __syncthreads();
        }
        if (t == 0) {
            out[PERP_OFF] = (float)exp(-part[0]);
            out[0] = (float)(part2[0] * 1.25 / (double)NELEM);
        }
    }
}

// ---------------------------------------------------------------------------
extern "C" void kernel_launch(void* const* d_in, const int* in_sizes, int n_in,
                              void* d_out, int out_size, void* d_ws, size_t ws_size,
                              hipStream_t stream) {
    const float* x  = (const float*)d_in[0];
    const float* cb = (const float*)d_in[1];
    float* out = (float*)d_out;
    char*  ws  = (char*)d_ws;

    unsigned* counts = (unsigned*)(ws + WS_COUNTS);
    double*   sumsq  = (double*)(ws + WS_SUMSQ);
    unsigned* rcnt   = (unsigned*)(ws + WS_RISKCNT);
    unsigned* done   = (unsigned*)(ws + WS_DONE);
    float*    en2    = (float*)(ws + WS_EN2);
    float*    xn2    = (float*)(ws + WS_XN2);
    int*      idxv   = (int*)(ws + WS_IDX);
    int*      rlist  = (int*)(ws + WS_RLIST);
    ull*      rkey   = (ull*)(ws + WS_RKEY);
    ushort*   efh    = (ushort*)(ws + WS_EHI);
    ushort*   xfh    = (ushort*)(ws + WS_XHI);
    ushort*   xfl    = (ushort*)(out + XLO_F_OFF);   // d_out Q region scratch
    // per-block sumsq partials: reuse rlist region (dead after k_rescan);
    // 1024 doubles = 8 KB << 128 KB, 8-byte aligned (270400 % 8 == 0)
    double*   psum   = (double*)(ws + WS_RLIST);

    k_pre<<<592, 256, 0, stream>>>(x, cb, xfh, xfl, xn2, efh, en2,
                                   rkey, counts, rcnt, done, sumsq);
    k_sweep<<<512, 256, 0, stream>>>(x, xfh, xfl, efh, en2, idxv, rlist, rcnt);
    k_rescan<<<512, 256, 0, stream>>>((const float*)xfh, (const float*)xfl,
                                      cb, en2, xn2, rlist, rcnt, rkey);
    k_gather<<<1024, 256, 0, stream>>>(x, cb, idxv, rkey, out, psum, counts, done);
}

// Round 9
// 189.735 us; speedup vs baseline: 1.3150x; 1.3150x over previous
//
#include <hip/hip_runtime.h>
#include <math.h>

// Problem constants
#define K_    1024
#define N_    32768
#define NELEM 8388608

// d_out layout (floats, reference return order)
#define Q_OFF    1
#define PERP_OFF 8388609
#define IDX_OFF  8388610

// d_out Q-region scratch (overwritten by k_gather at the end)
#define XLO_F_OFF 4          // xlo frag: 32768*256 fp16

typedef unsigned long long ull;
typedef _Float16 h8  __attribute__((ext_vector_type(8)));
typedef float    f4v __attribute__((ext_vector_type(4)));

// ws layout (bytes)
#define WS_COUNTS  0        // 1024 u32
#define WS_SUMSQ   4096     // double (legacy, unused by gather now)
#define WS_RISKCNT 4104     // u32
#define WS_DONE    4108     // u32
#define WS_EN2     4160     // 1024 f32
#define WS_XN2     8256     // 32768 f32
#define WS_IDX     139328   // 32768 i32
#define WS_RLIST   270400   // 32768 i32; REUSED by k_gather as 1024 f64 partials
#define WS_RKEY    401472   // 32768 u64
#define WS_EHI     663616   // 1024*256 fp16 (fragment-major)
#define WS_XHI     1187904  // 32768*256 fp16 (fragment-major)

// es LDS leading-dim: 133 (not 132) -> stores are 2-way instead of 8-way
// bank-conflicted (528a mod 32 = {0,16}; 532a mod 32 has period 8).
#define ES_LD 133

// risky-gap threshold, quantized (1/1024-scaled-distance grid):
// W = 0.20 scaled -> 205 grid + 2 quantization slack. Covers ref f32
// rounding (0.066) + 2x sweep dot error (max ~0.027 at 6 sigma; 15 sigma
// would be needed to break 0.134) + <=0.1 grid fused-epilogue rounding
// delta (enQ pre-fusion, see k_sweep). Flagged pixels get exact f32 rescan.
#define RISKY_Q 207u

// REGISTER LAW (R4/R5/R6/R8 — FOUR spill storms, lever RETIRED):
// On gfx950's unified 256-reg file, the MFMA accumulator (acc=128 AGPR for
// the 64-px sweep) is carved out FIRST; the arch-VGPR ceiling is therefore
// exactly 256 - acc = 128, NOT a soft budget. The R3 sweep body needs ~100
// arch regs -> only ~28 true headroom. Every attempt to spend more
// (8-wave split R4, 32-px+cap R5, slack-cap R6, ping-pong prefetch R8)
// crossed the ceiling and spilled 95-340 MB of scratch (WRITE_SIZE
// tripwire). Also: __launch_bounds__ min-waves is an allocator COMMAND
// (cap = 512/waves regs) — never set it above what acc+arch permit.
// The ONLY verified no-spill sweep: 64-px tile, 4 waves, acc=128,
// arch~100, (256,2), compiler-scheduled loads. DO NOT touch its inner loop.

__device__ __forceinline__ unsigned u32min(unsigned a, unsigned b) { return a < b ? a : b; }
__device__ __forceinline__ unsigned u32max(unsigned a, unsigned b) { return a > b ? a : b; }

// Release ordering for a preceding device-scope atomic WITHOUT the
// agent-scope fence's buffer_wbl2/buffer_inv (XCD-L2 writeback+invalidate
// storm). The atomic already executed at the coherent point; we only need
// its completion before the next atomic issues.
__device__ __forceinline__ void vmem_drain() {
    asm volatile("s_waitcnt vmcnt(0)" ::: "memory");
}

// ---------------------------------------------------------------------------
// k_pre: blocks 0..511: x -> fragment-major fp16 hi/lo + xn2.
//        blocks 512..527: codebook -> fragment-major fp16 hi + en2.
//        blocks 528..591: rkey init (+ block 528: counts/rcnt/done/sumsq).
// Fragment layout (halfwords):
//   xf: [pixblock 512][dc 8][pi 4][lane 64][j 8]; pixel=pi*16+(lane&15),
//       d = dc*32 + (lane>>4)*8 + j
//   ef: [kt 4][w 4][dc 8][ci 4][lane 64][j 8]; code=kt*256+w*64+ci*16+(lane&15)
__global__ __launch_bounds__(256) void k_pre(const float* __restrict__ x,
                                             const float* __restrict__ cb,
                                             ushort* __restrict__ xfh,
                                             ushort* __restrict__ xfl,
                                             float* __restrict__ xn2,
                                             ushort* __restrict__ efh,
                                             float* __restrict__ en2,
                                             ull* __restrict__ rkey,
                                             unsigned* __restrict__ counts,
                                             unsigned* __restrict__ rcnt,
                                             unsigned* __restrict__ done,
                                             double* __restrict__ sumsq) {
    __shared__ float T[256 * 68];
    __shared__ double red[256];
    const int t = threadIdx.x, bid = blockIdx.x;

    if (bid < 512) {
        const int b = bid >> 4, hw0 = (bid & 15) << 6;
        const float* xb = x + b * 262144 + hw0;
        // stage [c][p], quad-swizzled so frag reads are <=2-way bank aliased
#pragma unroll
        for (int i = 0; i < 16; ++i) {
            const int jv = i * 256 + t, c = jv >> 4, p4 = (jv & 15) << 2;
            const int sw = ((c >> 3) & 3) << 3;
            *(float4*)(&T[c * 68 + (p4 ^ sw)]) = *(const float4*)(xb + c * 1024 + p4);
        }
        __syncthreads();
        const int mi = t >> 6, lane = t & 63;
        const int quad = (t >> 4) & 3, l15 = t & 15;
        const int pxs = (mi * 16 + l15) ^ (quad << 3);
        double sn = 0.0;
        const size_t obase = (size_t)bid * 16384 + lane * 8;
#pragma unroll
        for (int dc = 0; dc < 8; ++dc) {
            union { _Float16 h[8]; int4 v; } ph, pl;
#pragma unroll
            for (int j = 0; j < 8; ++j) {
                const float v = T[(dc * 32 + quad * 8 + j) * 68 + pxs];
                sn += (double)v * v;
                const _Float16 hi = (_Float16)v;
                ph.h[j] = hi;
                pl.h[j] = (_Float16)((v - (float)hi) * 2048.0f);
            }
            *(int4*)(xfh + obase + (dc * 4 + mi) * 512) = ph.v;
            *(int4*)(xfl + obase + (dc * 4 + mi) * 512) = pl.v;
        }
        red[t] = sn;
        __syncthreads();
        if (t < 64) {
            const int base = (t >> 4) * 64 + (t & 15);
            xn2[bid * 64 + t] = (float)(red[base] + red[base + 16] +
                                        red[base + 32] + red[base + 48]);
        }
    } else if (bid < 528) {
        const int n = (bid - 512) * 64 + (t >> 2);
        const int seg = t & 3;
        const float* src = cb + (size_t)n * 256 + seg * 64;
        const int kt = n >> 8, wch = (n >> 6) & 3, ci = (n >> 4) & 3, l15 = n & 15;
        double s = 0.0;
#pragma unroll
        for (int g = 0; g < 8; ++g) {
            const float4 a = *(const float4*)(src + g * 8);
            const float4 b = *(const float4*)(src + g * 8 + 4);
            s += (double)a.x * a.x + (double)a.y * a.y + (double)a.z * a.z + (double)a.w * a.w;
            s += (double)b.x * b.x + (double)b.y * b.y + (double)b.z * b.z + (double)b.w * b.w;
            const float v[8] = {a.x, a.y, a.z, a.w, b.x, b.y, b.z, b.w};
            union { _Float16 h[8]; int4 q; } ph;
#pragma unroll
            for (int j = 0; j < 8; ++j)
                ph.h[j] = (_Float16)(v[j] * 1024.0f);          // exact pow2 scale
            const int dc = seg * 2 + (g >> 2);
            const int quad = g & 3;
            const size_t addr = ((size_t)(((kt * 4 + wch) * 8 + dc) * 4 + ci) * 64 +
                                 (quad * 16 + l15)) * 8;
            *(int4*)(efh + addr) = ph.q;
        }
        red[t] = s;
        __syncthreads();
        if (t < 64) {
            const int r2 = (bid - 512) * 64 + t;
            en2[r2] = (float)(red[t * 4] + red[t * 4 + 1] + red[t * 4 + 2] + red[t * 4 + 3]);
        }
    } else {
        const int ib = bid - 528;
        const int i0 = ib * 512 + t * 2;
        rkey[i0] = ~0ull; rkey[i0 + 1] = ~0ull;
        if (ib == 0) {
            ((uint4*)counts)[t] = make_uint4(0u, 0u, 0u, 0u);
            if (t == 0) { *rcnt = 0u; *done = 0u; *sumsq = 0.0; }
        }
    }
}

// ---------------------------------------------------------------------------
// 2-chain fp16 MFMA sweep, register epilogue — the VERIFIED 189.6µs shape
// (VGPR=100, no spill): 256 threads = 4 waves; block = 64 px x 1024 codes;
// wave w = codes [kt*256+w*64, +64). Compiler-scheduled A-loads (manual
// prefetch retired — see REGISTER LAW above).
// D layout: col(lane&15)=pixel, row(quad*4+reg)=code -> each lane owns 4
// pixels x 16 codes: per-pixel top-2 in registers as quantized u32 keys.
// Fused epilogue (validated R4-R8, absmax unchanged): enQ = en2*2^20 +
// 131072; qf = fmaf(-2048, acc_hi, enQ) - acc_lo == (dist_s+128)*1024.
// Tail phase gather-writes the exact f32 x rows of this block's risky
// pixels into the block's OWN (dead after staging) xfh/xfl segments
// ("x_t": ch 0..127 -> xfh seg, 128..255 -> xfl seg, 128 f32/px each):
// pays the stride-4096 line-amplified x gather ONCE, latency hidden
// across 512 concurrent blocks, instead of 8x inside k_rescan.
__global__ __launch_bounds__(256, 2) void k_sweep(const float* __restrict__ x,
                                                  ushort* __restrict__ xfh,
                                                  ushort* __restrict__ xfl,
                                                  const ushort* __restrict__ efh,
                                                  const float* __restrict__ en2,
                                                  int* __restrict__ idxv,
                                                  int* __restrict__ rlist,
                                                  unsigned* __restrict__ rcnt) {
    __shared__ __align__(16) ushort Bsh[16384];   // 32 KB: pixel-hi frags
    __shared__ __align__(16) ushort Bsl[16384];   // 32 KB: pixel-lo frags
    __shared__ __align__(16) float  enS[1024];    // 4 KB: fused norm keys
    __shared__ unsigned Mg[4][64][2];             // 2 KB: per-wave top-2
    __shared__ int rpixS[64];                     // local risky pixel list
    __shared__ int rnS;

    const int t = threadIdx.x, bid = blockIdx.x;
    const int p0 = bid << 6;
    const int w = t >> 6, lane = t & 63;
    const int quad = lane >> 4, l15 = lane & 15;

    {   // stage this block's 64 pixels (hi+lo) + fused norm keys
        const size_t base = (size_t)bid * 16384;
#pragma unroll
        for (int i = 0; i < 8; ++i) {
            const int off = (i * 256 + t) * 8;
            *(int4*)(&Bsh[off]) = *(const int4*)(xfh + base + off);
            *(int4*)(&Bsl[off]) = *(const int4*)(xfl + base + off);
        }
#pragma unroll
        for (int i = 0; i < 4; ++i)
            enS[i * 256 + t] = fmaf(en2[i * 256 + t], 1048576.0f, 131072.0f);
    }
    __syncthreads();
    // From here on the global xfh/xfl segments of THIS block are dead
    // (only block bid ever reads segment bid) -> reusable as x_t scratch.

    unsigned K1[4], K2[4];   // running top-2 per pixel (ni*16+l15)
#pragma unroll
    for (int ni = 0; ni < 4; ++ni) { K1[ni] = 0xFFFFFFFFu; K2[ni] = 0xFFFFFFFFu; }

    for (int kt = 0; kt < 4; ++kt) {
        const f4v z = {0.f, 0.f, 0.f, 0.f};
        f4v acc1[4][4], acc2[4][4];
#pragma unroll
        for (int mi = 0; mi < 4; ++mi)
#pragma unroll
            for (int ni = 0; ni < 4; ++ni) { acc1[mi][ni] = z; acc2[mi][ni] = z; }

#pragma unroll 2
        for (int dc = 0; dc < 8; ++dc) {
            h8 ah[4];
            const size_t abase = ((size_t)((kt * 4 + w) * 8 + dc) * 4) * 512 + lane * 8;
#pragma unroll
            for (int mi = 0; mi < 4; ++mi)
                ah[mi] = *(const h8*)(efh + abase + mi * 512);
            const int bbase = dc * 2048 + lane * 8;
#pragma unroll
            for (int ni = 0; ni < 4; ++ni) {
                const h8 bh = *(const h8*)(&Bsh[bbase + ni * 512]);
                const h8 bl = *(const h8*)(&Bsl[bbase + ni * 512]);
#pragma unroll
                for (int mi = 0; mi < 4; ++mi) {
                    acc1[mi][ni] = __builtin_amdgcn_mfma_f32_16x16x32_f16(
                        ah[mi], bh, acc1[mi][ni], 0, 0, 0);
                    acc2[mi][ni] = __builtin_amdgcn_mfma_f32_16x16x32_f16(
                        ah[mi], bl, acc2[mi][ni], 0, 0, 0);
                }
            }
        }
        // register epilogue: 64 dists -> quantized keys -> top-2 per pixel
#pragma unroll
        for (int mi = 0; mi < 4; ++mi) {
            const int cbase = kt * 256 + w * 64 + mi * 16 + quad * 4;
            const f4v enQ = *(const f4v*)(&enS[cbase]);   // b128, broadcast/2-way
#pragma unroll
            for (int ni = 0; ni < 4; ++ni) {
#pragma unroll
                for (int r = 0; r < 4; ++r) {
                    const float t0 = fmaf(-2048.0f, acc1[mi][ni][r], enQ[r]);
                    const float qf = t0 - acc2[mi][ni][r];
                    const unsigned key = ((unsigned)(int)qf << 10) | (unsigned)(cbase + r);
                    const unsigned o1 = K1[ni];
                    K1[ni] = u32min(o1, key);
                    K2[ni] = u32min(K2[ni], u32max(o1, key));
                }
            }
        }
    }
    // cross-quad merge (disjoint code sets, same pixels): xor 16, 32
#pragma unroll
    for (int m = 16; m <= 32; m <<= 1) {
#pragma unroll
        for (int ni = 0; ni < 4; ++ni) {
            const unsigned a1 = (unsigned)__shfl_xor((int)K1[ni], m, 64);
            const unsigned a2 = (unsigned)__shfl_xor((int)K2[ni], m, 64);
            const unsigned n1 = u32min(K1[ni], a1);
            const unsigned n2 = u32min(u32max(K1[ni], a1), u32min(K2[ni], a2));
            K1[ni] = n1; K2[ni] = n2;
        }
    }
    if (quad == 0) {
#pragma unroll
        for (int ni = 0; ni < 4; ++ni) {
            Mg[w][ni * 16 + l15][0] = K1[ni];
            Mg[w][ni * 16 + l15][1] = K2[ni];
        }
    }
    __syncthreads();
    if (t < 64) {   // cross-wave merge (disjoint code sets per wave)
        unsigned b1 = Mg[0][t][0], b2 = Mg[0][t][1];
#pragma unroll
        for (int ww = 1; ww < 4; ++ww) {
            const unsigned a1 = Mg[ww][t][0], a2 = Mg[ww][t][1];
            const unsigned n1 = u32min(b1, a1);
            b2 = u32min(u32max(b1, a1), u32min(b2, a2));
            b1 = n1;
        }
        const int P = p0 + t;
        idxv[P] = (int)(b1 & 1023u);
        const bool risky = ((b2 >> 10) - (b1 >> 10)) <= RISKY_Q;
        const ull mask = __ballot(risky);
        const int pre = __popcll(mask & ((1ull << t) - 1ull));
        unsigned base = 0;
        if (t == 0) { base = atomicAdd(rcnt, (unsigned)__popcll(mask)); rnS = (int)__popcll(mask); }
        base = (unsigned)__shfl((int)base, 0, 64);
        if (risky) { rlist[base + pre] = P; rpixS[pre] = t; }
    }
    __syncthreads();
    // x_t gather: exact f32 rows for this block's risky pixels into the
    // block's own dead frag segments. Wave-parallel over risky pixels; each
    // lane fetches 4 channels (4 stride-4096B scalar loads -> 4 lines) and
    // stores one contiguous float4 to the x_t row.
    {
        const int rn = rnS;
        float* xth = (float*)(xfh + (size_t)bid * 16384);   // 64 px * 128 f32
        float* xtl = (float*)(xfl + (size_t)bid * 16384);
        for (int i = w; i < rn; i += 4) {
            const int lp = rpixS[i];
            const int P = p0 + lp;
            const float* xp = x + (size_t)(P >> 10) * 262144 + (P & 1023);
            const int c0 = lane * 4;
            float4 vv;
            vv.x = xp[(size_t)(c0 + 0) * 1024];
            vv.y = xp[(size_t)(c0 + 1) * 1024];
            vv.z = xp[(size_t)(c0 + 2) * 1024];
            vv.w = xp[(size_t)(c0 + 3) * 1024];
            float* dst = (c0 < 128) ? (xth + lp * 128 + c0)
                                    : (xtl + lp * 128 + (c0 - 128));
            *(float4*)dst = vv;
        }
    }
}

// ---------------------------------------------------------------------------
// Exact f32 rescan of risky pixels (validated: replicates np ref numerics).
// x is read from x_t (pixel-major exact f32 rows written by k_sweep into
// the dead xfh/xfl segments): per thread 4x float4 from ONE cache line,
// L2-resident, instead of 16 stride-4096 scalar gathers (16 lines) re-done
// per kt-unit. Staged values and accumulation order are bit-identical.
__global__ __launch_bounds__(256) void k_rescan(const float* __restrict__ xth,
                                                const float* __restrict__ xtl,
                                                const float* __restrict__ cb,
                                                const float* __restrict__ en2,
                                                const float* __restrict__ xn2,
                                                const int* __restrict__ rlist,
                                                const unsigned* __restrict__ rcnt,
                                                ull* __restrict__ rkey) {
    __shared__ float xs[64 * 68];
    __shared__ float es[64 * ES_LD];
    __shared__ int plist[64];
    const int t = threadIdx.x;
    const unsigned cnt = *rcnt;
    const int nunits = (int)(((cnt + 63) >> 6) << 3);
    const int ti = t >> 4, tj = t & 15;

    for (int u = blockIdx.x; u < nunits; u += gridDim.x) {
        const int tile = u >> 3, kt = u & 7;
        __syncthreads();
        if (t < 64) {
            const int li = tile * 64 + t;
            plist[t] = rlist[li < (int)cnt ? li : 0];
        }
        __syncthreads();

        float xnr[4]; int pid[4];
#pragma unroll
        for (int r = 0; r < 4; ++r) {
            pid[r] = plist[ti * 4 + r];
            xnr[r] = xn2[pid[r]];
        }
        float acc[4][8];
#pragma unroll
        for (int r = 0; r < 4; ++r)
#pragma unroll
            for (int j = 0; j < 8; ++j) acc[r][j] = 0.f;
        float best_s[4]; int best_k[4];
#pragma unroll
        for (int r = 0; r < 4; ++r) { best_s[r] = INFINITY; best_k[r] = 0; }

        for (int dc = 0; dc < 4; ++dc) {
            __syncthreads();
            {   // coalesced x_t stage: 64 B contiguous per thread
                const int p = t & 63, coff = t >> 6;
                const int P = plist[p];
                const size_t rbase = (size_t)(P >> 6) * 8192 + (size_t)(P & 63) * 128;
                const int c0 = dc * 64 + coff * 16;
                const float* src = (c0 < 128) ? (xth + rbase + c0)
                                              : (xtl + rbase + (c0 - 128));
#pragma unroll
                for (int q = 0; q < 4; ++q) {
                    const float4 v = *(const float4*)(src + q * 4);
                    const int cl = coff * 16 + q * 4;
                    xs[(cl + 0) * 68 + p] = v.x;
                    xs[(cl + 1) * 68 + p] = v.y;
                    xs[(cl + 2) * 68 + p] = v.z;
                    xs[(cl + 3) * 68 + p] = v.w;
                }
            }
#pragma unroll
            for (int i = 0; i < 8; ++i) {
                const int jv = i * 256 + t, k = jv >> 4, d4 = (jv & 15) << 2;
                const float4 v = *(const float4*)(cb + (size_t)(kt * 128 + k) * 256 + dc * 64 + d4);
                es[(d4 + 0) * ES_LD + k] = v.x; es[(d4 + 1) * ES_LD + k] = v.y;
                es[(d4 + 2) * ES_LD + k] = v.z; es[(d4 + 3) * ES_LD + k] = v.w;
            }
            __syncthreads();
#pragma unroll 4
            for (int d = 0; d < 64; ++d) {
                const float4 xv = *(const float4*)(&xs[d * 68 + ti * 4]);
                const float4 e0 = *(const float4*)(&es[d * ES_LD + tj * 8]);
                const float4 e1 = *(const float4*)(&es[d * ES_LD + tj * 8 + 4]);
                const float xr[4] = {xv.x, xv.y, xv.z, xv.w};
                const float ej[8] = {e0.x, e0.y, e0.z, e0.w, e1.x, e1.y, e1.z, e1.w};
#pragma unroll
                for (int r = 0; r < 4; ++r)
#pragma unroll
                    for (int j = 0; j < 8; ++j)
                        acc[r][j] = fmaf(xr[r], ej[j], acc[r][j]);
            }
        }
#pragma unroll
        for (int j = 0; j < 8; ++j) {
            const int k = kt * 128 + tj * 8 + j;
            const float en = en2[k];
#pragma unroll
            for (int r = 0; r < 4; ++r) {
                const float s1 = xnr[r] + en;
                const float dist = fmaf(-2.f, acc[r][j], s1);
                if (dist < best_s[r] || (dist == best_s[r] && k < best_k[r])) {
                    best_s[r] = dist; best_k[r] = k;
                }
            }
        }
#pragma unroll
        for (int r = 0; r < 4; ++r) {
            float s = best_s[r]; int k = best_k[r];
            for (int m = 1; m < 16; m <<= 1) {
                const float s2 = __shfl_xor(s, m, 64);
                const int k2 = __shfl_xor(k, m, 64);
                if (s2 < s || (s2 == s && k2 < k)) { s = s2; k = k2; }
            }
            if (tj == 0 && (tile * 64 + ti * 4 + r) < (int)cnt) {
                const ull key = ((ull)__float_as_uint(s) << 32) | (unsigned)k;  // dist>0
                atomicMin(&rkey[pid[r]], key);
            }
        }
    }
}

// ---------------------------------------------------------------------------
// Gather (+resolve fused) -> q_out, (q-x)^2 sum, histogram, idx_f; the LAST
// block (device-scope done-counter) computes loss + perplexity.
// NOTE: no __threadfence() anywhere — on gfx950 an agent-scope fence emits
// buffer_wbl2/buffer_inv (full XCD-L2 writeback+invalidate). 1024 blocks
// each flushing/invalidating the L2 mid-stream was the serializer. The only
// ordering needed (psum atomicExch completes before done increment) is a
// plain s_waitcnt vmcnt(0): both ops are device-scope atomics at the
// coherent point.
__global__ __launch_bounds__(256) void k_gather(const float* __restrict__ x,
                                                const float* __restrict__ cb,
                                                const int* __restrict__ idxv,
                                                const ull* __restrict__ rkey,
                                                float* __restrict__ out,
                                                double* __restrict__ psum,
                                                unsigned* __restrict__ counts,
                                                unsigned* __restrict__ done) {
    __shared__ __align__(16) float cs[32 * 260];
    __shared__ int   kidx[32];
    __shared__ float wpart[4];
    __shared__ int   lastf;
    __shared__ double part[256];
    __shared__ double part2[256];

    const int t = threadIdx.x, bid = blockIdx.x;
    const int n0 = bid * 32;
    if (t < 32) {
        const int n = n0 + t;
        const ull rk = rkey[n];
        const int kk = (rk != ~0ull) ? (int)(unsigned)(rk & 0xffffffffu) : idxv[n];
        kidx[t] = kk;
        atomicAdd(&counts[kk], 1u);
        out[IDX_OFF + n] = (float)kk;
    }
    if (t == 0) lastf = 0;
    __syncthreads();
#pragma unroll
    for (int i = 0; i < 8; ++i) {
        int jv = (i << 8) + t;
        int p = jv >> 6, c4 = (jv & 63) << 2;
        const float4 v = *(const float4*)(cb + (size_t)kidx[p] * 256 + c4);
        *(float4*)(&cs[p * 260 + c4]) = v;
    }
    __syncthreads();

    const int b = bid >> 5, h = bid & 31;
    const float* xb = x + b * 262144 + h * 32;
    float* qb = out + Q_OFF + b * 262144 + h * 32;

    float local = 0.f;
#pragma unroll
    for (int i = 0; i < 8; ++i) {
        int j = (i << 8) + t;
        int c = j >> 3, w4 = (j & 7) << 2;
        const float q0 = cs[(w4 + 0) * 260 + c];
        const float q1 = cs[(w4 + 1) * 260 + c];
        const float q2 = cs[(w4 + 2) * 260 + c];
        const float q3 = cs[(w4 + 3) * 260 + c];
        const float4 xv = *(const float4*)(xb + c * 1024 + w4);
        const float d0 = q0 - xv.x, d1 = q1 - xv.y;
        const float d2 = q2 - xv.z, d3 = q3 - xv.w;
        local += d0 * d0 + d1 * d1 + d2 * d2 + d3 * d3;
        qb[c * 1024 + w4 + 0] = q0;
        qb[c * 1024 + w4 + 1] = q1;
        qb[c * 1024 + w4 + 2] = q2;
        qb[c * 1024 + w4 + 3] = q3;
    }
    for (int m = 32; m > 0; m >>= 1) local += __shfl_down(local, m, 64);
    if ((t & 63) == 0) wpart[t >> 6] = local;
    __syncthreads();
    if (t == 0) {
        const double bs = (double)wpart[0] + (double)wpart[1] +
                          (double)wpart[2] + (double)wpart[3];
        // contention-free: native 64b exchange to this block's own slot
        atomicExch((ull*)&psum[bid], (ull)__double_as_longlong(bs));
        vmem_drain();   // release: swap reached coherent point; NO wbl2/inv
        if (atomicAdd(done, 1u) == 1023u) lastf = 1;
    }
    __syncthreads();
    if (lastf) {
        double s = 0.0, ss = 0.0;
        for (int k = t; k < K_; k += 256) {
            const unsigned c = atomicAdd(&counts[k], 0u);   // coherent read
            const double p = (double)c / (double)N_;
            s += p * log(p + 1e-10);
        }
#pragma unroll
        for (int i = 0; i < 4; ++i) {
            const ull pv = atomicAdd((ull*)&psum[i * 256 + t], 0ull);  // coherent read
            ss += __longlong_as_double((long long)pv);
        }
        part[t] = s; part2[t] = ss;
        __syncthreads();
        for (int off = 128; off > 0; off >>= 1) {
            if (t < off) { part[t] += part[t + off]; part2[t] += part2[t + off]; }
            __syncthreads();
        }
        if (t == 0) {
            out[PERP_OFF] = (float)exp(-part[0]);
            out[0] = (float)(part2[0] * 1.25 / (double)NELEM);
        }
    }
}

// ---------------------------------------------------------------------------
extern "C" void kernel_launch(void* const* d_in, const int* in_sizes, int n_in,
                              void* d_out, int out_size, void* d_ws, size_t ws_size,
                              hipStream_t stream) {
    const float* x  = (const float*)d_in[0];
    const float* cb = (const float*)d_in[1];
    float* out = (float*)d_out;
    char*  ws  = (char*)d_ws;

    unsigned* counts = (unsigned*)(ws + WS_COUNTS);
    double*   sumsq  = (double*)(ws + WS_SUMSQ);
    unsigned* rcnt   = (unsigned*)(ws + WS_RISKCNT);
    unsigned* done   = (unsigned*)(ws + WS_DONE);
    float*    en2    = (float*)(ws + WS_EN2);
    float*    xn2    = (float*)(ws + WS_XN2);
    int*      idxv   = (int*)(ws + WS_IDX);
    int*      rlist  = (int*)(ws + WS_RLIST);
    ull*      rkey   = (ull*)(ws + WS_RKEY);
    ushort*   efh    = (ushort*)(ws + WS_EHI);
    ushort*   xfh    = (ushort*)(ws + WS_XHI);
    ushort*   xfl    = (ushort*)(out + XLO_F_OFF);   // d_out Q region scratch
    // per-block sumsq partials: reuse rlist region (dead after k_rescan);
    // 1024 doubles = 8 KB << 128 KB, 8-byte aligned (270400 % 8 == 0)
    double*   psum   = (double*)(ws + WS_RLIST);

    k_pre<<<592, 256, 0, stream>>>(x, cb, xfh, xfl, xn2, efh, en2,
                                   rkey, counts, rcnt, done, sumsq);
    k_sweep<<<512, 256, 0, stream>>>(x, xfh, xfl, efh, en2, idxv, rlist, rcnt);
    k_rescan<<<512, 256, 0, stream>>>((const float*)xfh, (const float*)xfl,
                                      cb, en2, xn2, rlist, rcnt, rkey);
    k_gather<<<1024, 256, 0, stream>>>(x, cb, idxv, rkey, out, psum, counts, done);
}

// Round 10
// 184.052 us; speedup vs baseline: 1.3556x; 1.0309x over previous
//
#include <hip/hip_runtime.h>
#include <math.h>

// Problem constants
#define K_    1024
#define N_    32768
#define NELEM 8388608

// d_out layout (floats, reference return order)
#define Q_OFF    1
#define PERP_OFF 8388609
#define IDX_OFF  8388610

// d_out Q-region scratch (x_t lo half lives here; overwritten by k_gather)
#define XLO_F_OFF 4

typedef unsigned long long ull;
typedef _Float16 h8  __attribute__((ext_vector_type(8)));
typedef float    f4v __attribute__((ext_vector_type(4)));

// ws layout (bytes)
#define WS_COUNTS  0        // 1024 u32
#define WS_SUMSQ   4096     // double (legacy)
#define WS_RISKCNT 4104     // u32
#define WS_DONE    4108     // u32
#define WS_EN2     4160     // 1024 f32
#define WS_XN2     8256     // 32768 f32
#define WS_IDX     139328   // 32768 i32
#define WS_RLIST   270400   // 32768 i32; REUSED by k_gather as 1024 f64 partials
#define WS_RKEY    401472   // 32768 u64
#define WS_EHI     663616   // 1024*256 fp16 (fragment-major)
#define WS_XHI     1187904  // now PURE x_t scratch (fp16 frag round-trip fused away)

// es LDS leading-dim: 133 (not 132) -> stores are 2-way instead of 8-way
// bank-conflicted.
#define ES_LD 133

// risky-gap threshold, quantized (1/1024-scaled-distance grid):
// W = 0.20 scaled -> 205 grid + 2 quantization slack. Covers ref f32
// rounding (0.066) + 2x sweep dot error (max ~0.027 at 6 sigma; 15 sigma
// would be needed to break 0.134) + <=0.1 grid fused-epilogue rounding
// delta (enQ pre-fusion). Flagged pixels get exact f32 rescan.
#define RISKY_Q 207u

// REGISTER LAW (R4/R5/R6/R8 — FOUR spill storms, lever RETIRED):
// On gfx950's unified 256-reg file the MFMA accumulator (acc=128 AGPR for
// the 64-px sweep) is carved out FIRST; arch-VGPR ceiling = 256 - acc = 128
// exactly. The sweep body needs ~100 arch -> ~28 true headroom. Every
// attempt to spend more (R4 8-wave, R5 32-px+cap, R6 slack-cap, R8
// ping-pong prefetch) spilled 95-340 MB scratch (WRITE_SIZE tripwire).
// __launch_bounds__ min-waves is an allocator COMMAND (cap = 512/waves).
// Verified no-spill sweep: 64-px, 4 waves, acc=128, (256,2),
// compiler-scheduled loads. Inner loop untouchable.
// R10 FUSION: k_pre's x->frag conversion moved into k_sweep's PROLOGUE
// (frags born in LDS, 64 MB HBM round-trip + one 512-block launch
// eliminated). Prologue registers die before acc/K1/K2 live ranges open.
// LDS budget: 32768+32768+4096+8704+2048(union)+260 = 80644 <= 81920
// (2 blocks/CU boundary). Tripwire: LDS_Block_Size > 81920 -> revert.

__device__ __forceinline__ unsigned u32min(unsigned a, unsigned b) { return a < b ? a : b; }
__device__ __forceinline__ unsigned u32max(unsigned a, unsigned b) { return a > b ? a : b; }

// Release ordering for a preceding device-scope atomic WITHOUT the
// agent-scope fence's buffer_wbl2/buffer_inv (XCD-L2 writeback+invalidate
// storm — R2's fix, -35 µs).
__device__ __forceinline__ void vmem_drain() {
    asm volatile("s_waitcnt vmcnt(0)" ::: "memory");
}

// ---------------------------------------------------------------------------
// k_pre0: blocks 0..15: codebook -> fragment-major fp16 + en2.
//         blocks 16..79: rkey init (+ block 16: counts/rcnt/done/sumsq).
// (x->frag work moved into k_sweep's prologue, R10.)
// ef frag layout (halfwords): [kt 4][w 4][dc 8][ci 4][lane 64][j 8];
// code = kt*256 + w*64 + ci*16 + (lane&15).
__global__ __launch_bounds__(256) void k_pre0(const float* __restrict__ cb,
                                              ushort* __restrict__ efh,
                                              float* __restrict__ en2,
                                              ull* __restrict__ rkey,
                                              unsigned* __restrict__ counts,
                                              unsigned* __restrict__ rcnt,
                                              unsigned* __restrict__ done,
                                              double* __restrict__ sumsq) {
    __shared__ double red[256];
    const int t = threadIdx.x, bid = blockIdx.x;

    if (bid < 16) {
        const int n = bid * 64 + (t >> 2);
        const int seg = t & 3;
        const float* src = cb + (size_t)n * 256 + seg * 64;
        const int kt = n >> 8, wch = (n >> 6) & 3, ci = (n >> 4) & 3, l15 = n & 15;
        double s = 0.0;
#pragma unroll
        for (int g = 0; g < 8; ++g) {
            const float4 a = *(const float4*)(src + g * 8);
            const float4 b = *(const float4*)(src + g * 8 + 4);
            s += (double)a.x * a.x + (double)a.y * a.y + (double)a.z * a.z + (double)a.w * a.w;
            s += (double)b.x * b.x + (double)b.y * b.y + (double)b.z * b.z + (double)b.w * b.w;
            const float v[8] = {a.x, a.y, a.z, a.w, b.x, b.y, b.z, b.w};
            union { _Float16 h[8]; int4 q; } ph;
#pragma unroll
            for (int j = 0; j < 8; ++j)
                ph.h[j] = (_Float16)(v[j] * 1024.0f);          // exact pow2 scale
            const int dc = seg * 2 + (g >> 2);
            const int quad = g & 3;
            const size_t addr = ((size_t)(((kt * 4 + wch) * 8 + dc) * 4 + ci) * 64 +
                                 (quad * 16 + l15)) * 8;
            *(int4*)(efh + addr) = ph.q;
        }
        red[t] = s;
        __syncthreads();
        if (t < 64) {
            const int r2 = bid * 64 + t;
            en2[r2] = (float)(red[t * 4] + red[t * 4 + 1] + red[t * 4 + 2] + red[t * 4 + 3]);
        }
    } else {
        const int ib = bid - 16;
        const int i0 = ib * 512 + t * 2;
        rkey[i0] = ~0ull; rkey[i0 + 1] = ~0ull;
        if (ib == 0) {
            ((uint4*)counts)[t] = make_uint4(0u, 0u, 0u, 0u);
            if (t == 0) { *rcnt = 0u; *done = 0u; *sumsq = 0.0; }
        }
    }
}

// ---------------------------------------------------------------------------
// FUSED pre+sweep (R10). Prologue: stage this block's 64 px x 256 ch of x
// through a swizzled 32-ch LDS tile T8 (8 chunks), convert to fp16 hi/lo
// fragments DIRECTLY into Bsh/Bsl (no global frag round-trip), accumulate
// xn2 via red (LDS union with Mg; red read completes before the barrier
// preceding the kt loop, Mg written only after it).
// Swizzle correctness (same as old k_pre): store T8[lc*68 + (p4^sw)],
// sw=((lc>>3)&3)<<3; read T8[(quad*8+j)*68 + pxs], pxs=(mi*16+l15)^(quad<<3)
// -> the two XORs cancel, thread (mi,quad,l15) reads pixel mi*16+l15. The
// staged values and cvt chain are bit-identical to k_pre's.
// Sweep body: the VERIFIED 189.6µs shape (VGPR=92, no spill), 4 waves,
// 64 px x 1024 codes, compiler-scheduled A-loads, fused enQ epilogue.
// Tail: x_t gather of risky pixels' exact f32 rows into xfh/xfl scratch
// (now pure scratch — nothing else writes it).
__global__ __launch_bounds__(256, 2) void k_sweep(const float* __restrict__ x,
                                                  ushort* __restrict__ xfh,
                                                  ushort* __restrict__ xfl,
                                                  const ushort* __restrict__ efh,
                                                  const float* __restrict__ en2,
                                                  float* __restrict__ xn2,
                                                  int* __restrict__ idxv,
                                                  int* __restrict__ rlist,
                                                  unsigned* __restrict__ rcnt) {
    __shared__ __align__(16) ushort Bsh[16384];   // 32 KB: pixel-hi frags
    __shared__ __align__(16) ushort Bsl[16384];   // 32 KB: pixel-lo frags
    __shared__ __align__(16) float  enS[1024];    // 4 KB: fused norm keys
    __shared__ __align__(16) float  T8[32 * 68];  // 8.5 KB: x staging chunk
    __shared__ union { unsigned mg[4][64][2]; double red[256]; } U;  // 2 KB
    __shared__ int rpixS[64];                     // local risky pixel list
    __shared__ int rnS;

    const int t = threadIdx.x, bid = blockIdx.x;
    const int p0 = bid << 6;
    const int w = t >> 6, lane = t & 63;
    const int quad = lane >> 4, l15 = lane & 15;

    // ---- prologue: x -> frags in LDS + xn2 (was k_pre blocks 0..511) ----
    {
        const int b = bid >> 4, hw0 = (bid & 15) << 6;
        const float* xb = x + b * 262144 + hw0;
        const int quad_p = (t >> 4) & 3;                 // = quad
        const int pxs = (w * 16 + l15) ^ (quad_p << 3);
        double sn = 0.0;
        for (int dc = 0; dc < 8; ++dc) {
#pragma unroll
            for (int i = 0; i < 2; ++i) {
                const int jv = i * 256 + t, lc = jv >> 4, p4 = (jv & 15) << 2;
                const int sw = ((lc >> 3) & 3) << 3;
                *(float4*)(&T8[lc * 68 + (p4 ^ sw)]) =
                    *(const float4*)(xb + (dc * 32 + lc) * 1024 + p4);
            }
            __syncthreads();
            union { _Float16 h[8]; int4 v; } ph, pl;
#pragma unroll
            for (int j = 0; j < 8; ++j) {
                const float v = T8[(quad_p * 8 + j) * 68 + pxs];
                sn += (double)v * v;
                const _Float16 hi = (_Float16)v;
                ph.h[j] = hi;
                pl.h[j] = (_Float16)((v - (float)hi) * 2048.0f);
            }
            *(int4*)(&Bsh[(dc * 4 + w) * 512 + lane * 8]) = ph.v;
            *(int4*)(&Bsl[(dc * 4 + w) * 512 + lane * 8]) = pl.v;
            __syncthreads();   // T8 reused next chunk
        }
        U.red[t] = sn;
        __syncthreads();
        if (t < 64) {
            const int base = (t >> 4) * 64 + (t & 15);
            xn2[bid * 64 + t] = (float)(U.red[base] + U.red[base + 16] +
                                        U.red[base + 32] + U.red[base + 48]);
        }
#pragma unroll
        for (int i = 0; i < 4; ++i)
            enS[i * 256 + t] = fmaf(en2[i * 256 + t], 1048576.0f, 131072.0f);
        __syncthreads();   // red read + enS stores complete; U free for Mg
    }

    unsigned K1[4], K2[4];   // running top-2 per pixel (ni*16+l15)
#pragma unroll
    for (int ni = 0; ni < 4; ++ni) { K1[ni] = 0xFFFFFFFFu; K2[ni] = 0xFFFFFFFFu; }

    for (int kt = 0; kt < 4; ++kt) {
        const f4v z = {0.f, 0.f, 0.f, 0.f};
        f4v acc1[4][4], acc2[4][4];
#pragma unroll
        for (int mi = 0; mi < 4; ++mi)
#pragma unroll
            for (int ni = 0; ni < 4; ++ni) { acc1[mi][ni] = z; acc2[mi][ni] = z; }

#pragma unroll 2
        for (int dc = 0; dc < 8; ++dc) {
            h8 ah[4];
            const size_t abase = ((size_t)((kt * 4 + w) * 8 + dc) * 4) * 512 + lane * 8;
#pragma unroll
            for (int mi = 0; mi < 4; ++mi)
                ah[mi] = *(const h8*)(efh + abase + mi * 512);
            const int bbase = dc * 2048 + lane * 8;
#pragma unroll
            for (int ni = 0; ni < 4; ++ni) {
                const h8 bh = *(const h8*)(&Bsh[bbase + ni * 512]);
                const h8 bl = *(const h8*)(&Bsl[bbase + ni * 512]);
#pragma unroll
                for (int mi = 0; mi < 4; ++mi) {
                    acc1[mi][ni] = __builtin_amdgcn_mfma_f32_16x16x32_f16(
                        ah[mi], bh, acc1[mi][ni], 0, 0, 0);
                    acc2[mi][ni] = __builtin_amdgcn_mfma_f32_16x16x32_f16(
                        ah[mi], bl, acc2[mi][ni], 0, 0, 0);
                }
            }
        }
        // register epilogue: 64 dists -> quantized keys -> top-2 per pixel
#pragma unroll
        for (int mi = 0; mi < 4; ++mi) {
            const int cbase = kt * 256 + w * 64 + mi * 16 + quad * 4;
            const f4v enQ = *(const f4v*)(&enS[cbase]);   // b128, broadcast/2-way
#pragma unroll
            for (int ni = 0; ni < 4; ++ni) {
#pragma unroll
                for (int r = 0; r < 4; ++r) {
                    const float t0 = fmaf(-2048.0f, acc1[mi][ni][r], enQ[r]);
                    const float qf = t0 - acc2[mi][ni][r];
                    const unsigned key = ((unsigned)(int)qf << 10) | (unsigned)(cbase + r);
                    const unsigned o1 = K1[ni];
                    K1[ni] = u32min(o1, key);
                    K2[ni] = u32min(K2[ni], u32max(o1, key));
                }
            }
        }
    }
    // cross-quad merge (disjoint code sets, same pixels): xor 16, 32
#pragma unroll
    for (int m = 16; m <= 32; m <<= 1) {
#pragma unroll
        for (int ni = 0; ni < 4; ++ni) {
            const unsigned a1 = (unsigned)__shfl_xor((int)K1[ni], m, 64);
            const unsigned a2 = (unsigned)__shfl_xor((int)K2[ni], m, 64);
            const unsigned n1 = u32min(K1[ni], a1);
            const unsigned n2 = u32min(u32max(K1[ni], a1), u32min(K2[ni], a2));
            K1[ni] = n1; K2[ni] = n2;
        }
    }
    if (quad == 0) {
#pragma unroll
        for (int ni = 0; ni < 4; ++ni) {
            U.mg[w][ni * 16 + l15][0] = K1[ni];
            U.mg[w][ni * 16 + l15][1] = K2[ni];
        }
    }
    __syncthreads();
    if (t < 64) {   // cross-wave merge (disjoint code sets per wave)
        unsigned b1 = U.mg[0][t][0], b2 = U.mg[0][t][1];
#pragma unroll
        for (int ww = 1; ww < 4; ++ww) {
            const unsigned a1 = U.mg[ww][t][0], a2 = U.mg[ww][t][1];
            const unsigned n1 = u32min(b1, a1);
            b2 = u32min(u32max(b1, a1), u32min(b2, a2));
            b1 = n1;
        }
        const int P = p0 + t;
        idxv[P] = (int)(b1 & 1023u);
        const bool risky = ((b2 >> 10) - (b1 >> 10)) <= RISKY_Q;
        const ull mask = __ballot(risky);
        const int pre = __popcll(mask & ((1ull << t) - 1ull));
        unsigned base = 0;
        if (t == 0) { base = atomicAdd(rcnt, (unsigned)__popcll(mask)); rnS = (int)__popcll(mask); }
        base = (unsigned)__shfl((int)base, 0, 64);
        if (risky) { rlist[base + pre] = P; rpixS[pre] = t; }
    }
    __syncthreads();
    // x_t gather: exact f32 rows for this block's risky pixels into the
    // block's own xfh/xfl scratch segments (pure scratch post-fusion).
    {
        const int rn = rnS;
        float* xth = (float*)(xfh + (size_t)bid * 16384);   // 64 px * 128 f32
        float* xtl = (float*)(xfl + (size_t)bid * 16384);
        for (int i = w; i < rn; i += 4) {
            const int lp = rpixS[i];
            const int P = p0 + lp;
            const float* xp = x + (size_t)(P >> 10) * 262144 + (P & 1023);
            const int c0 = lane * 4;
            float4 vv;
            vv.x = xp[(size_t)(c0 + 0) * 1024];
            vv.y = xp[(size_t)(c0 + 1) * 1024];
            vv.z = xp[(size_t)(c0 + 2) * 1024];
            vv.w = xp[(size_t)(c0 + 3) * 1024];
            float* dst = (c0 < 128) ? (xth + lp * 128 + c0)
                                    : (xtl + lp * 128 + (c0 - 128));
            *(float4*)dst = vv;
        }
    }
}

// ---------------------------------------------------------------------------
// Exact f32 rescan of risky pixels (validated: replicates np ref numerics).
// x read from x_t (pixel-major exact f32 rows from k_sweep's tail): per
// thread 4x float4 from ONE cache line, L2-resident. Bit-identical staging.
__global__ __launch_bounds__(256) void k_rescan(const float* __restrict__ xth,
                                                const float* __restrict__ xtl,
                                                const float* __restrict__ cb,
                                                const float* __restrict__ en2,
                                                const float* __restrict__ xn2,
                                                const int* __restrict__ rlist,
                                                const unsigned* __restrict__ rcnt,
                                                ull* __restrict__ rkey) {
    __shared__ float xs[64 * 68];
    __shared__ float es[64 * ES_LD];
    __shared__ int plist[64];
    const int t = threadIdx.x;
    const unsigned cnt = *rcnt;
    const int nunits = (int)(((cnt + 63) >> 6) << 3);
    const int ti = t >> 4, tj = t & 15;

    for (int u = blockIdx.x; u < nunits; u += gridDim.x) {
        const int tile = u >> 3, kt = u & 7;
        __syncthreads();
        if (t < 64) {
            const int li = tile * 64 + t;
            plist[t] = rlist[li < (int)cnt ? li : 0];
        }
        __syncthreads();

        float xnr[4]; int pid[4];
#pragma unroll
        for (int r = 0; r < 4; ++r) {
            pid[r] = plist[ti * 4 + r];
            xnr[r] = xn2[pid[r]];
        }
        float acc[4][8];
#pragma unroll
        for (int r = 0; r < 4; ++r)
#pragma unroll
            for (int j = 0; j < 8; ++j) acc[r][j] = 0.f;
        float best_s[4]; int best_k[4];
#pragma unroll
        for (int r = 0; r < 4; ++r) { best_s[r] = INFINITY; best_k[r] = 0; }

        for (int dc = 0; dc < 4; ++dc) {
            __syncthreads();
            {   // coalesced x_t stage: 64 B contiguous per thread
                const int p = t & 63, coff = t >> 6;
                const int P = plist[p];
                const size_t rbase = (size_t)(P >> 6) * 8192 + (size_t)(P & 63) * 128;
                const int c0 = dc * 64 + coff * 16;
                const float* src = (c0 < 128) ? (xth + rbase + c0)
                                              : (xtl + rbase + (c0 - 128));
#pragma unroll
                for (int q = 0; q < 4; ++q) {
                    const float4 v = *(const float4*)(src + q * 4);
                    const int cl = coff * 16 + q * 4;
                    xs[(cl + 0) * 68 + p] = v.x;
                    xs[(cl + 1) * 68 + p] = v.y;
                    xs[(cl + 2) * 68 + p] = v.z;
                    xs[(cl + 3) * 68 + p] = v.w;
                }
            }
#pragma unroll
            for (int i = 0; i < 8; ++i) {
                const int jv = i * 256 + t, k = jv >> 4, d4 = (jv & 15) << 2;
                const float4 v = *(const float4*)(cb + (size_t)(kt * 128 + k) * 256 + dc * 64 + d4);
                es[(d4 + 0) * ES_LD + k] = v.x; es[(d4 + 1) * ES_LD + k] = v.y;
                es[(d4 + 2) * ES_LD + k] = v.z; es[(d4 + 3) * ES_LD + k] = v.w;
            }
            __syncthreads();
#pragma unroll 4
            for (int d = 0; d < 64; ++d) {
                const float4 xv = *(const float4*)(&xs[d * 68 + ti * 4]);
                const float4 e0 = *(const float4*)(&es[d * ES_LD + tj * 8]);
                const float4 e1 = *(const float4*)(&es[d * ES_LD + tj * 8 + 4]);
                const float xr[4] = {xv.x, xv.y, xv.z, xv.w};
                const float ej[8] = {e0.x, e0.y, e0.z, e0.w, e1.x, e1.y, e1.z, e1.w};
#pragma unroll
                for (int r = 0; r < 4; ++r)
#pragma unroll
                    for (int j = 0; j < 8; ++j)
                        acc[r][j] = fmaf(xr[r], ej[j], acc[r][j]);
            }
        }
#pragma unroll
        for (int j = 0; j < 8; ++j) {
            const int k = kt * 128 + tj * 8 + j;
            const float en = en2[k];
#pragma unroll
            for (int r = 0; r < 4; ++r) {
                const float s1 = xnr[r] + en;
                const float dist = fmaf(-2.f, acc[r][j], s1);
                if (dist < best_s[r] || (dist == best_s[r] && k < best_k[r])) {
                    best_s[r] = dist; best_k[r] = k;
                }
            }
        }
#pragma unroll
        for (int r = 0; r < 4; ++r) {
            float s = best_s[r]; int k = best_k[r];
            for (int m = 1; m < 16; m <<= 1) {
                const float s2 = __shfl_xor(s, m, 64);
                const int k2 = __shfl_xor(k, m, 64);
                if (s2 < s || (s2 == s && k2 < k)) { s = s2; k = k2; }
            }
            if (tj == 0 && (tile * 64 + ti * 4 + r) < (int)cnt) {
                const ull key = ((ull)__float_as_uint(s) << 32) | (unsigned)k;  // dist>0
                atomicMin(&rkey[pid[r]], key);
            }
        }
    }
}

// ---------------------------------------------------------------------------
// Gather (+resolve fused) -> q_out, (q-x)^2 sum, histogram, idx_f; the LAST
// block (device-scope done-counter) computes loss + perplexity.
// No __threadfence() (gfx950 agent fences emit buffer_wbl2/buffer_inv —
// XCD-L2 flush storm, R2's fix). psum = per-block slots (no shared-address
// FP atomic, R0's fix).
__global__ __launch_bounds__(256) void k_gather(const float* __restrict__ x,
                                                const float* __restrict__ cb,
                                                const int* __restrict__ idxv,
                                                const ull* __restrict__ rkey,
                                                float* __restrict__ out,
                                                double* __restrict__ psum,
                                                unsigned* __restrict__ counts,
                                                unsigned* __restrict__ done) {
    __shared__ __align__(16) float cs[32 * 260];
    __shared__ int   kidx[32];
    __shared__ float wpart[4];
    __shared__ int   lastf;
    __shared__ double part[256];
    __shared__ double part2[256];

    const int t = threadIdx.x, bid = blockIdx.x;
    const int n0 = bid * 32;
    if (t < 32) {
        const int n = n0 + t;
        const ull rk = rkey[n];
        const int kk = (rk != ~0ull) ? (int)(unsigned)(rk & 0xffffffffu) : idxv[n];
        kidx[t] = kk;
        atomicAdd(&counts[kk], 1u);
        out[IDX_OFF + n] = (float)kk;
    }
    if (t == 0) lastf = 0;
    __syncthreads();
#pragma unroll
    for (int i = 0; i < 8; ++i) {
        int jv = (i << 8) + t;
        int p = jv >> 6, c4 = (jv & 63) << 2;
        const float4 v = *(const float4*)(cb + (size_t)kidx[p] * 256 + c4);
        *(float4*)(&cs[p * 260 + c4]) = v;
    }
    __syncthreads();

    const int b = bid >> 5, h = bid & 31;
    const float* xb = x + b * 262144 + h * 32;
    float* qb = out + Q_OFF + b * 262144 + h * 32;

    float local = 0.f;
#pragma unroll
    for (int i = 0; i < 8; ++i) {
        int j = (i << 8) + t;
        int c = j >> 3, w4 = (j & 7) << 2;
        const float q0 = cs[(w4 + 0) * 260 + c];
        const float q1 = cs[(w4 + 1) * 260 + c];
        const float q2 = cs[(w4 + 2) * 260 + c];
        const float q3 = cs[(w4 + 3) * 260 + c];
        const float4 xv = *(const float4*)(xb + c * 1024 + w4);
        const float d0 = q0 - xv.x, d1 = q1 - xv.y;
        const float d2 = q2 - xv.z, d3 = q3 - xv.w;
        local += d0 * d0 + d1 * d1 + d2 * d2 + d3 * d3;
        qb[c * 1024 + w4 + 0] = q0;
        qb[c * 1024 + w4 + 1] = q1;
        qb[c * 1024 + w4 + 2] = q2;
        qb[c * 1024 + w4 + 3] = q3;
    }
    for (int m = 32; m > 0; m >>= 1) local += __shfl_down(local, m, 64);
    if ((t & 63) == 0) wpart[t >> 6] = local;
    __syncthreads();
    if (t == 0) {
        const double bs = (double)wpart[0] + (double)wpart[1] +
                          (double)wpart[2] + (double)wpart[3];
        atomicExch((ull*)&psum[bid], (ull)__double_as_longlong(bs));
        vmem_drain();   // release: swap reached coherent point; NO wbl2/inv
        if (atomicAdd(done, 1u) == 1023u) lastf = 1;
    }
    __syncthreads();
    if (lastf) {
        double s = 0.0, ss = 0.0;
        for (int k = t; k < K_; k += 256) {
            const unsigned c = atomicAdd(&counts[k], 0u);   // coherent read
            const double p = (double)c / (double)N_;
            s += p * log(p + 1e-10);
        }
#pragma unroll
        for (int i = 0; i < 4; ++i) {
            const ull pv = atomicAdd((ull*)&psum[i * 256 + t], 0ull);  // coherent read
            ss += __longlong_as_double((long long)pv);
        }
        part[t] = s; part2[t] = ss;
        __syncthreads();
        for (int off = 128; off > 0; off >>= 1) {
            if (t < off) { part[t] += part[t + off]; part2[t] += part2[t + off]; }
            __syncthreads();
        }
        if (t == 0) {
            out[PERP_OFF] = (float)exp(-part[0]);
            out[0] = (float)(part2[0] * 1.25 / (double)NELEM);
        }
    }
}

// ---------------------------------------------------------------------------
extern "C" void kernel_launch(void* const* d_in, const int* in_sizes, int n_in,
                              void* d_out, int out_size, void* d_ws, size_t ws_size,
                              hipStream_t stream) {
    const float* x  = (const float*)d_in[0];
    const float* cb = (const float*)d_in[1];
    float* out = (float*)d_out;
    char*  ws  = (char*)d_ws;

    unsigned* counts = (unsigned*)(ws + WS_COUNTS);
    double*   sumsq  = (double*)(ws + WS_SUMSQ);
    unsigned* rcnt   = (unsigned*)(ws + WS_RISKCNT);
    unsigned* done   = (unsigned*)(ws + WS_DONE);
    float*    en2    = (float*)(ws + WS_EN2);
    float*    xn2    = (float*)(ws + WS_XN2);
    int*      idxv   = (int*)(ws + WS_IDX);
    int*      rlist  = (int*)(ws + WS_RLIST);
    ull*      rkey   = (ull*)(ws + WS_RKEY);
    ushort*   efh    = (ushort*)(ws + WS_EHI);
    ushort*   xfh    = (ushort*)(ws + WS_XHI);     // x_t hi-half scratch
    ushort*   xfl    = (ushort*)(out + XLO_F_OFF); // x_t lo-half scratch (d_out Q region)
    double*   psum   = (double*)(ws + WS_RLIST);   // per-block sumsq partials

    k_pre0<<<80, 256, 0, stream>>>(cb, efh, en2, rkey, counts, rcnt, done, sumsq);
    k_sweep<<<512, 256, 0, stream>>>(x, xfh, xfl, efh, en2, xn2, idxv, rlist, rcnt);
    k_rescan<<<512, 256, 0, stream>>>((const float*)xfh, (const float*)xfl,
                                      cb, en2, xn2, rlist, rcnt, rkey);
    k_gather<<<1024, 256, 0, stream>>>(x, cb, idxv, rkey, out, psum, counts, done);
}